// Round 3
// baseline (192.335 us; speedup 1.0000x reference)
//
#include <hip/hip_runtime.h>

// Problem constants
#define BQ 4
#define SQ 4096
#define HIDN 768
#define NH 12
#define DH 64
#define BH (BQ * NH)          // 48
#define WIN 128
#define MROWS (BQ * SQ)       // 16384
#define NCOLS (3 * HIDN)      // 2304
#define KDIM HIDN             // 768
#define BHD_ELEMS (BH * SQ * DH)   // 12582912

using bfrag = __attribute__((ext_vector_type(8))) short;   // 8 bf16 (4 VGPRs)
using f32x4 = __attribute__((ext_vector_type(4))) float;   // 4 fp32 acc

__device__ __forceinline__ unsigned short f2bf(float f) {
  union { float f; unsigned u; } x; x.f = f;
  unsigned r = x.u + 0x7fffu + ((x.u >> 16) & 1u);   // RNE
  return (unsigned short)(r >> 16);
}
__device__ __forceinline__ unsigned f2bf2(float lo, float hi) {
  return (unsigned)f2bf(lo) | ((unsigned)f2bf(hi) << 16);
}

__device__ __forceinline__ void gload16(const void* g, void* l) {
  __builtin_amdgcn_global_load_lds(
      (const __attribute__((address_space(1))) unsigned int*)g,
      (__attribute__((address_space(3))) unsigned int*)l, 16, 0, 0);
}

// ---------------- kernel 0a: convert Wq|Wk|Wv fp32 -> bf16 [2304][768] ----------------
__global__ __launch_bounds__(256) void wconv_kernel(
    const float* __restrict__ Wq, const float* __restrict__ Wk,
    const float* __restrict__ Wv, unsigned short* __restrict__ wb)
{
  int i = blockIdx.x * 256 + threadIdx.x;           // one thread = 4 elems
  int g = i * 4;
  if (g >= NCOLS * KDIM) return;
  int n = g / KDIM, k = g - n * KDIM;
  int wsel = n / HIDN, nl = n - wsel * HIDN;
  const float* W = (wsel == 0) ? Wq : (wsel == 1) ? Wk : Wv;
  float4 v = *reinterpret_cast<const float4*>(&W[nl * KDIM + k]);
  ushort4 p;
  p.x = f2bf(v.x); p.y = f2bf(v.y); p.z = f2bf(v.z); p.w = f2bf(v.w);
  *reinterpret_cast<ushort4*>(&wb[g]) = p;
}

// ---------------- kernel 0b: convert hidden fp32 -> bf16 [16384][768] ----------------
__global__ __launch_bounds__(256) void hconv_kernel(
    const float* __restrict__ hid, unsigned short* __restrict__ hb)
{
  const int N8 = MROWS * KDIM / 8;                  // 1572864 items of 8 elems
  for (int idx = blockIdx.x * 256 + threadIdx.x; idx < N8; idx += gridDim.x * 256) {
    const float4* src = reinterpret_cast<const float4*>(hid) + (size_t)idx * 2;
    float4 a = src[0], b = src[1];
    uint4 o;
    o.x = f2bf2(a.x, a.y); o.y = f2bf2(a.z, a.w);
    o.z = f2bf2(b.x, b.y); o.w = f2bf2(b.z, b.w);
    *reinterpret_cast<uint4*>(&hb[(size_t)idx * 8]) = o;
  }
}

// ---------------- kernel 1: fused QKV projection (bf16 MFMA) ----------------
// C[m][n] = sum_k hb[m][k]*wb[n][k] + bias[n]; M=16384 N=2304 K=768
// BK=64, T2 XOR-swizzled LDS (linear gload_lds dest + inverse-swizzled global src),
// swapped-operand MFMA so each lane holds 4 consecutive d -> 8B stores.
#define BM 128
#define BN 128
#define BKK 64

__global__ __launch_bounds__(256) void proj_kernel(
    const unsigned short* __restrict__ hb,
    const unsigned short* __restrict__ wb,
    const float* __restrict__ bq, const float* __restrict__ bk,
    const float* __restrict__ bv,
    unsigned short* __restrict__ qb, unsigned short* __restrict__ kb,
    unsigned short* __restrict__ vb)
{
  __shared__ unsigned short As[BM][BKK];
  __shared__ unsigned short Bs[BN][BKK];

  const int t = threadIdx.x;
  // XCD-bijective swizzle: 2304 blocks, 2304%8==0 -> chunk 288 per XCD
  const int id = blockIdx.x;
  const int swz = (id & 7) * (NCOLS * MROWS / (BM * BN) / 8) + (id >> 3);
  const int bx = swz % (NCOLS / BN);    // 18 N-tiles (A-panel reuse within XCD)
  const int by = swz / (NCOLS / BN);    // 128 M-tiles
  const int m0 = by * BM;
  const int n0 = bx * BN;
  const int wsel = bx / 6;              // 0=q 1=k 2=v (each 6 N-tiles)
  const float* bias = (wsel == 0) ? bq : (wsel == 1) ? bk : bv;
  const int nloc0 = n0 - wsel * HIDN;

  const int lane = t & 63;
  const int w = t >> 6;
  const int wm = w >> 1, wn = w & 1;
  const int fr = lane & 15, fq = lane >> 4;
  const int xsw = (fr & 7) << 3;        // read-side XOR (elem units)

  // staging: wave w owns rows w*32..+31; inst i covers 8 rows (64 lanes x 16B = 1KB)
  // LDS dest linear; global src col inverse-swizzled: elem = ((l&7)*8) ^ ((l>>3)<<3)
  const int srow = w * 32 + (lane >> 3);
  const int scol = ((lane & 7) * 8) ^ ((lane >> 3) << 3);
  const unsigned short* gA = &hb[(size_t)(m0 + srow) * KDIM + scol];
  const unsigned short* gB = &wb[(size_t)(n0 + srow) * KDIM + scol];

  f32x4 acc[4][4] = {};

  for (int kt = 0; kt < KDIM / BKK; ++kt) {
    const int k0 = kt * BKK;
    __syncthreads();                                 // prev compute's ds_reads done
    #pragma unroll
    for (int i = 0; i < 4; ++i) {
      gload16(gA + k0 + (size_t)(i * 8) * KDIM, &As[w * 32 + i * 8][0]);
      gload16(gB + k0 + (size_t)(i * 8) * KDIM, &Bs[w * 32 + i * 8][0]);
    }
    __syncthreads();                                 // loads landed
    #pragma unroll
    for (int kk = 0; kk < 2; ++kk) {
      bfrag a[4], b[4];
      #pragma unroll
      for (int i = 0; i < 4; ++i)
        a[i] = *reinterpret_cast<const bfrag*>(&As[wm * 64 + i * 16 + fr][(kk * 32 + fq * 8) ^ xsw]);
      #pragma unroll
      for (int j = 0; j < 4; ++j)
        b[j] = *reinterpret_cast<const bfrag*>(&Bs[wn * 64 + j * 16 + fr][(kk * 32 + fq * 8) ^ xsw]);
      #pragma unroll
      for (int i = 0; i < 4; ++i)
        #pragma unroll
        for (int j = 0; j < 4; ++j)
          acc[i][j] = __builtin_amdgcn_mfma_f32_16x16x32_bf16(b[j], a[i], acc[i][j], 0, 0, 0);
    }
  }

  // epilogue: D-row <-> n (4 consecutive per lane), D-col <-> m. 8B stores.
  unsigned short* outb = (wsel == 0) ? qb : (wsel == 1) ? kb : vb;
  const float qscale = (wsel == 0) ? 0.125f : 1.0f;   // fold 1/sqrt(64) into q
  const int b_ = m0 >> 12;                             // batch (BM | 4096)
  #pragma unroll
  for (int j = 0; j < 4; ++j) {
    int nl = nloc0 + wn * 64 + j * 16 + fq * 4;        // 4 consecutive n
    int h = nl >> 6, d0 = nl & 63;
    float4 bs4 = *reinterpret_cast<const float4*>(&bias[nl]);
    unsigned short* obase = outb + (size_t)(b_ * NH + h) * SQ * DH + d0;
    #pragma unroll
    for (int i = 0; i < 4; ++i) {
      int m = m0 + wm * 64 + i * 16 + fr;              // D-col = lane&15
      int srow_ = m & (SQ - 1);
      f32x4 v = acc[i][j];
      uint2 pk;
      pk.x = f2bf2((v[0] + bs4.x) * qscale, (v[1] + bs4.y) * qscale);
      pk.y = f2bf2((v[2] + bs4.z) * qscale, (v[3] + bs4.w) * qscale);
      *reinterpret_cast<uint2*>(&obase[(size_t)srow_ * DH]) = pk;
    }
  }
}

// ---------------- kernel 2: sliding-window attention ----------------
// block = (head bh, 64-query chunk c); 4 waves x 16 queries
// T14 async V staging: issue global loads to regs early (2 phases), LDS-write late,
// ONE barrier; swapped QK^T; per-wave P-LDS roundtrip for PV.
#define VLD 344    // 320 real keys + 24 pad (zeroed)
#define NITEMS (86 * 16)   // 1376 (kg 0..85 x dg 0..15)

__device__ __forceinline__ void load_vitem(
    const unsigned short* __restrict__ Vbh, int kstart, int it, ushort4 v[4])
{
  int kg = it >> 4, dg = it & 15;
  int kr = kstart + kg * 4;
  #pragma unroll
  for (int rr = 0; rr < 4; ++rr) {
    int k = kr + rr;
    int kc = k < 0 ? 0 : (k > SQ - 1 ? SQ - 1 : k);
    v[rr] = *reinterpret_cast<const ushort4*>(&Vbh[(size_t)kc * DH + dg * 4]);
  }
}

__global__ __launch_bounds__(256) void attn_kernel(
    const unsigned short* __restrict__ qb,
    const unsigned short* __restrict__ kb,
    const unsigned short* __restrict__ vb,
    float* __restrict__ out)
{
  __shared__ unsigned short Vt[DH][VLD];       // V^T for this block's key range
  __shared__ unsigned short Pl[4][16][40];     // per-wave P tile

  const int bh = blockIdx.x;
  const int c = blockIdx.y;
  const int t = threadIdx.x;
  const int lane = t & 63;
  const int w = t >> 6;
  const int b_ = bh / NH, h = bh - b_ * NH;
  const int fr = lane & 15, fq = lane >> 4;

  const unsigned short* Qbh = qb + bh * (SQ * DH);
  const unsigned short* Kbh = kb + bh * (SQ * DH);
  const unsigned short* Vbh = vb + bh * (SQ * DH);

  const int kstart = c * 64 - WIN;             // block key range: [kstart, kstart+344)

  // write one transposed item to Vt (zeroing invalid keys)
  auto write_vitem = [&](int it, ushort4 v[4]) {
    int kg = it >> 4, dg = it & 15;
    int key0 = kg * 4, kr = kstart + key0;
    #pragma unroll
    for (int rr = 0; rr < 4; ++rr) {
      bool val = (key0 + rr < 320) && (kr + rr >= 0) && (kr + rr < SQ);
      if (!val) { v[rr].x = 0; v[rr].y = 0; v[rr].z = 0; v[rr].w = 0; }
    }
    ushort4 p0 = {v[0].x, v[1].x, v[2].x, v[3].x};
    ushort4 p1 = {v[0].y, v[1].y, v[2].y, v[3].y};
    ushort4 p2 = {v[0].z, v[1].z, v[2].z, v[3].z};
    ushort4 p3 = {v[0].w, v[1].w, v[2].w, v[3].w};
    *reinterpret_cast<ushort4*>(&Vt[dg * 4 + 0][key0]) = p0;
    *reinterpret_cast<ushort4*>(&Vt[dg * 4 + 1][key0]) = p1;
    *reinterpret_cast<ushort4*>(&Vt[dg * 4 + 2][key0]) = p2;
    *reinterpret_cast<ushort4*>(&Vt[dg * 4 + 3][key0]) = p3;
  };

  // ---- phase A: issue first 768 V items (3 per thread) ----
  ushort4 vA[3][4];
  #pragma unroll
  for (int p = 0; p < 3; ++p)
    load_vitem(Vbh, kstart, t + p * 256, vA[p]);

  // ---- QK^T ----
  const int q0 = c * 64 + w * 16;              // this wave's 16 queries
  const int kw = q0 - WIN;                     // wave key range start (17 tiles)
  bfrag qf0 = *reinterpret_cast<const bfrag*>(&Qbh[(q0 + fr) * DH + fq * 8]);
  bfrag qf1 = *reinterpret_cast<const bfrag*>(&Qbh[(q0 + fr) * DH + 32 + fq * 8]);

  float sc[17][4];
  #pragma unroll
  for (int tt = 0; tt < 17; ++tt) {
    int krow = kw + tt * 16 + fr;
    int kc = krow < 0 ? 0 : (krow >= SQ ? SQ - 1 : krow);   // clamp; masked later
    bfrag kf0 = *reinterpret_cast<const bfrag*>(&Kbh[kc * DH + fq * 8]);
    bfrag kf1 = *reinterpret_cast<const bfrag*>(&Kbh[kc * DH + 32 + fq * 8]);
    f32x4 d = {};
    __builtin_amdgcn_s_setprio(1);
    d = __builtin_amdgcn_mfma_f32_16x16x32_bf16(kf0, qf0, d, 0, 0, 0);
    d = __builtin_amdgcn_mfma_f32_16x16x32_bf16(kf1, qf1, d, 0, 0, 0);
    __builtin_amdgcn_s_setprio(0);
    #pragma unroll
    for (int r = 0; r < 4; ++r) sc[tt][r] = d[r];
  }

  // ---- write phase A to LDS; issue phase B ----
  #pragma unroll
  for (int p = 0; p < 3; ++p)
    write_vitem(t + p * 256, vA[p]);

  ushort4 vB[3][4];
  #pragma unroll
  for (int p = 0; p < 3; ++p) {
    int it = t + 768 + p * 256;
    if (it < NITEMS) load_vitem(Vbh, kstart, it, vB[p]);
  }

  // ---- mask + softmax ----
  const int q = q0 + fr;                       // this lane's query (col)
  #pragma unroll
  for (int tt = 0; tt < 17; ++tt)
    #pragma unroll
    for (int r = 0; r < 4; ++r) {
      int key = kw + tt * 16 + fq * 4 + r;     // row = (lane>>4)*4+r
      int dk = key - q;
      bool valid = (dk >= -WIN) && (dk <= WIN) && (key >= 0) && (key < SQ);
      if (!valid) sc[tt][r] = -1e30f;
    }

  float mx = -1e30f;
  #pragma unroll
  for (int tt = 0; tt < 17; ++tt)
    #pragma unroll
    for (int r = 0; r < 4; ++r) mx = fmaxf(mx, sc[tt][r]);
  mx = fmaxf(mx, __shfl_xor(mx, 16));
  mx = fmaxf(mx, __shfl_xor(mx, 32));

  float sum = 0.f;
  #pragma unroll
  for (int tt = 0; tt < 17; ++tt)
    #pragma unroll
    for (int r = 0; r < 4; ++r) {
      float p = __expf(sc[tt][r] - mx);
      sc[tt][r] = p;
      sum += p;
    }
  sum += __shfl_xor(sum, 16);
  sum += __shfl_xor(sum, 32);
  const float rinv = 1.0f / sum;

  // ---- write phase B; single barrier ----
  #pragma unroll
  for (int p = 0; p < 3; ++p) {
    int it = t + 768 + p * 256;
    if (it < NITEMS) write_vitem(it, vB[p]);
  }
  __syncthreads();

  // ---- PV: 9 K-steps of 32 keys ----
  f32x4 ctx[4] = {};
  #pragma unroll
  for (int ks = 0; ks < 9; ++ks) {
    unsigned short (&P)[16][40] = Pl[w];
    #pragma unroll
    for (int half = 0; half < 2; ++half) {
      int tt = ks * 2 + half;
      unsigned p01 = 0, p23 = 0;
      if (tt < 17) {
        p01 = f2bf2(sc[tt][0] * rinv, sc[tt][1] * rinv);
        p23 = f2bf2(sc[tt][2] * rinv, sc[tt][3] * rinv);
      }
      *reinterpret_cast<unsigned*>(&P[fr][half * 16 + fq * 4]) = p01;
      *reinterpret_cast<unsigned*>(&P[fr][half * 16 + fq * 4 + 2]) = p23;
    }
    asm volatile("s_waitcnt lgkmcnt(0)" ::: "memory");
    bfrag pa = *reinterpret_cast<const bfrag*>(&P[fr][fq * 8]);
    __builtin_amdgcn_s_setprio(1);
    #pragma unroll
    for (int nt = 0; nt < 4; ++nt) {
      const bfrag vf = *reinterpret_cast<const bfrag*>(
          &Vt[nt * 16 + fr][w * 16 + ks * 32 + fq * 8]);
      ctx[nt] = __builtin_amdgcn_mfma_f32_16x16x32_bf16(pa, vf, ctx[nt], 0, 0, 0);
    }
    __builtin_amdgcn_s_setprio(0);
  }

  // write ctx: row=(lane>>4)*4+r = q, col=lane&15 = d (within nt block)
  #pragma unroll
  for (int nt = 0; nt < 4; ++nt)
    #pragma unroll
    for (int r = 0; r < 4; ++r) {
      int qq = fq * 4 + r;
      int d = nt * 16 + fr;
      out[(size_t)(b_ * SQ + q0 + qq) * HIDN + h * DH + d] = ctx[nt][r];
    }
}

extern "C" void kernel_launch(void* const* d_in, const int* in_sizes, int n_in,
                              void* d_out, int out_size, void* d_ws, size_t ws_size,
                              hipStream_t stream) {
  const float* hid = (const float*)d_in[0];
  const float* Wq  = (const float*)d_in[1];
  const float* bq  = (const float*)d_in[2];
  const float* Wk  = (const float*)d_in[3];
  const float* bk  = (const float*)d_in[4];
  const float* Wv  = (const float*)d_in[5];
  const float* bv  = (const float*)d_in[6];
  float* out = (float*)d_out;

  // ws layout: qb | kb | vb (bf16 [48][4096][64] each) | wb bf16 [2304][768] | hb bf16 [16384][768]
  unsigned short* qb = (unsigned short*)d_ws;
  unsigned short* kb = qb + BHD_ELEMS;
  unsigned short* vb = kb + BHD_ELEMS;
  unsigned short* wb = vb + BHD_ELEMS;
  unsigned short* hb = wb + NCOLS * KDIM;

  int nconv = (NCOLS * KDIM / 4 + 255) / 256;
  wconv_kernel<<<dim3(nconv), dim3(256), 0, stream>>>(Wq, Wk, Wv, wb);
  hconv_kernel<<<dim3(2048), dim3(256), 0, stream>>>(hid, hb);

  dim3 g1(NCOLS * MROWS / (BM * BN));   // 2304, swizzled in-kernel
  proj_kernel<<<g1, dim3(256), 0, stream>>>(hb, wb, bq, bk, bv, qb, kb, vb);

  dim3 g2(BH, SQ / 64);
  attn_kernel<<<g2, dim3(256), 0, stream>>>(qb, kb, vb, out);
}

// Round 4
// 150.691 us; speedup vs baseline: 1.2764x; 1.2764x over previous
//
#include <hip/hip_runtime.h>

// Problem constants
#define BQ 4
#define SQ 4096
#define HIDN 768
#define NH 12
#define DH 64
#define BH (BQ * NH)          // 48
#define WIN 128
#define MROWS (BQ * SQ)       // 16384
#define NCOLS (3 * HIDN)      // 2304
#define KDIM HIDN             // 768
#define BHD_ELEMS (BH * SQ * DH)   // 12582912

using bfrag  = __attribute__((ext_vector_type(8))) short;    // 8 bf16 (4 VGPRs)
using f32x4  = __attribute__((ext_vector_type(4))) float;
using f32x16 = __attribute__((ext_vector_type(16))) float;
using us8    = __attribute__((ext_vector_type(8))) unsigned short;

__device__ __forceinline__ unsigned short f2bf(float f) {
  union { float f; unsigned u; } x; x.f = f;
  unsigned r = x.u + 0x7fffu + ((x.u >> 16) & 1u);   // RNE
  return (unsigned short)(r >> 16);
}
__device__ __forceinline__ unsigned f2bf2(float lo, float hi) {
  return (unsigned)f2bf(lo) | ((unsigned)f2bf(hi) << 16);
}
__device__ __forceinline__ unsigned cvtpk(float lo, float hi) {
  unsigned u;
  asm("v_cvt_pk_bf16_f32 %0, %1, %2" : "=v"(u) : "v"(lo), "v"(hi));
  return u;
}

__device__ __forceinline__ void gload16(const void* g, void* l) {
  __builtin_amdgcn_global_load_lds(
      (const __attribute__((address_space(1))) unsigned int*)g,
      (__attribute__((address_space(3))) unsigned int*)l, 16, 0, 0);
}

// ---------------- kernel 0a: convert Wq|Wk|Wv fp32 -> bf16 [2304][768] ----------------
__global__ __launch_bounds__(256) void wconv_kernel(
    const float* __restrict__ Wq, const float* __restrict__ Wk,
    const float* __restrict__ Wv, unsigned short* __restrict__ wb)
{
  int i = blockIdx.x * 256 + threadIdx.x;
  int g = i * 4;
  if (g >= NCOLS * KDIM) return;
  int n = g / KDIM, k = g - n * KDIM;
  int wsel = n / HIDN, nl = n - wsel * HIDN;
  const float* W = (wsel == 0) ? Wq : (wsel == 1) ? Wk : Wv;
  float4 v = *reinterpret_cast<const float4*>(&W[nl * KDIM + k]);
  ushort4 p;
  p.x = f2bf(v.x); p.y = f2bf(v.y); p.z = f2bf(v.z); p.w = f2bf(v.w);
  *reinterpret_cast<ushort4*>(&wb[g]) = p;
}

// ---------------- kernel 0b: convert hidden fp32 -> bf16 [16384][768] ----------------
__global__ __launch_bounds__(256) void hconv_kernel(
    const float* __restrict__ hid, unsigned short* __restrict__ hb)
{
  const int N8 = MROWS * KDIM / 8;
  for (int idx = blockIdx.x * 256 + threadIdx.x; idx < N8; idx += gridDim.x * 256) {
    const float4* src = reinterpret_cast<const float4*>(hid) + (size_t)idx * 2;
    float4 a = src[0], b = src[1];
    uint4 o;
    o.x = f2bf2(a.x, a.y); o.y = f2bf2(a.z, a.w);
    o.z = f2bf2(b.x, b.y); o.w = f2bf2(b.z, b.w);
    *reinterpret_cast<uint4*>(&hb[(size_t)idx * 8]) = o;
  }
}

// ---------------- kernel 1: fused QKV projection (bf16 MFMA) ----------------
#define BM 128
#define BN 128
#define BKK 64

__global__ __launch_bounds__(256) void proj_kernel(
    const unsigned short* __restrict__ hb,
    const unsigned short* __restrict__ wb,
    const float* __restrict__ bq, const float* __restrict__ bk,
    const float* __restrict__ bv,
    unsigned short* __restrict__ qb, unsigned short* __restrict__ kb,
    unsigned short* __restrict__ vb)
{
  __shared__ unsigned short As[BM][BKK];
  __shared__ unsigned short Bs[BN][BKK];

  const int t = threadIdx.x;
  const int id = blockIdx.x;
  const int swz = (id & 7) * (NCOLS * MROWS / (BM * BN) / 8) + (id >> 3);
  const int bx = swz % (NCOLS / BN);
  const int by = swz / (NCOLS / BN);
  const int m0 = by * BM;
  const int n0 = bx * BN;
  const int wsel = bx / 6;
  const float* bias = (wsel == 0) ? bq : (wsel == 1) ? bk : bv;
  const int nloc0 = n0 - wsel * HIDN;

  const int lane = t & 63;
  const int w = t >> 6;
  const int wm = w >> 1, wn = w & 1;
  const int fr = lane & 15, fq = lane >> 4;
  const int xsw = (fr & 7) << 3;

  const int srow = w * 32 + (lane >> 3);
  const int scol = ((lane & 7) * 8) ^ ((lane >> 3) << 3);
  const unsigned short* gA = &hb[(size_t)(m0 + srow) * KDIM + scol];
  const unsigned short* gB = &wb[(size_t)(n0 + srow) * KDIM + scol];

  f32x4 acc[4][4] = {};

  for (int kt = 0; kt < KDIM / BKK; ++kt) {
    const int k0 = kt * BKK;
    __syncthreads();
    #pragma unroll
    for (int i = 0; i < 4; ++i) {
      gload16(gA + k0 + (size_t)(i * 8) * KDIM, &As[w * 32 + i * 8][0]);
      gload16(gB + k0 + (size_t)(i * 8) * KDIM, &Bs[w * 32 + i * 8][0]);
    }
    __syncthreads();
    #pragma unroll
    for (int kk = 0; kk < 2; ++kk) {
      bfrag a[4], b[4];
      #pragma unroll
      for (int i = 0; i < 4; ++i)
        a[i] = *reinterpret_cast<const bfrag*>(&As[wm * 64 + i * 16 + fr][(kk * 32 + fq * 8) ^ xsw]);
      #pragma unroll
      for (int j = 0; j < 4; ++j)
        b[j] = *reinterpret_cast<const bfrag*>(&Bs[wn * 64 + j * 16 + fr][(kk * 32 + fq * 8) ^ xsw]);
      #pragma unroll
      for (int i = 0; i < 4; ++i)
        #pragma unroll
        for (int j = 0; j < 4; ++j)
          acc[i][j] = __builtin_amdgcn_mfma_f32_16x16x32_bf16(b[j], a[i], acc[i][j], 0, 0, 0);
    }
  }

  unsigned short* outb = (wsel == 0) ? qb : (wsel == 1) ? kb : vb;
  // fold 1/sqrt(64) AND log2(e) into q so attention scores are in exp2 domain
  const float qscale = (wsel == 0) ? 0.125f * 1.44269504088896f : 1.0f;
  const int b_ = m0 >> 12;
  #pragma unroll
  for (int j = 0; j < 4; ++j) {
    int nl = nloc0 + wn * 64 + j * 16 + fq * 4;
    int h = nl >> 6, d0 = nl & 63;
    float4 bs4 = *reinterpret_cast<const float4*>(&bias[nl]);
    unsigned short* obase = outb + (size_t)(b_ * NH + h) * SQ * DH + d0;
    #pragma unroll
    for (int i = 0; i < 4; ++i) {
      int m = m0 + wm * 64 + i * 16 + fr;
      int srow_ = m & (SQ - 1);
      f32x4 v = acc[i][j];
      uint2 pk;
      pk.x = f2bf2((v[0] + bs4.x) * qscale, (v[1] + bs4.y) * qscale);
      pk.y = f2bf2((v[2] + bs4.z) * qscale, (v[3] + bs4.w) * qscale);
      *reinterpret_cast<uint2*>(&obase[(size_t)srow_ * DH]) = pk;
    }
  }
}

// ---------------- kernel 2: sliding-window flash attention (32x32 MFMA) ----------------
// block = (128-query chunk c, head bh); 4 waves x 32 queries.
// Swapped QK^T (mfma(K,Q) -> D[key][q]): lane holds 16 keys of ONE q column.
// Online softmax (defer-max, exp2 domain). P->A-frag via cvt_pk + shfl_xor(32).
#define VLD 392          // 384 keys + 8 pad (stride 196 dwords -> b128 at conflict floor)
#define THR 11.6f        // defer-max threshold (8 nats in log2 units)

__global__ __launch_bounds__(256, 3) void attn_kernel(
    const unsigned short* __restrict__ qb,
    const unsigned short* __restrict__ kb,
    const unsigned short* __restrict__ vb,
    float* __restrict__ out)
{
  __shared__ unsigned short Vt[DH][VLD];     // V^T for this block's 384-key range

  const int c = blockIdx.x;                  // query chunk (32)
  const int bh = blockIdx.y;                 // head (48)
  const int t = threadIdx.x;
  const int lane = t & 63;
  const int w = t >> 6;
  const int b_ = bh / NH, hd = bh - b_ * NH;
  const int qi = lane & 31, h = lane >> 5;

  const unsigned short* Qbh = qb + bh * (SQ * DH);
  const unsigned short* Kbh = kb + bh * (SQ * DH);
  const unsigned short* Vbh = vb + bh * (SQ * DH);

  const int kstart = c * 128 - WIN;          // block key range [kstart, kstart+384)

  // ---- stage V^T: item = (kg 0..47 [8 keys], dg 0..15 [4 d]); 16B LDS writes ----
  for (int it = t; it < 48 * 16; it += 256) {
    int dg = it & 15, kg = it >> 4;
    int kr = kstart + kg * 8;
    ushort4 va[8];
    #pragma unroll
    for (int rr = 0; rr < 8; ++rr) {
      int k = kr + rr;
      int kc = k < 0 ? 0 : (k > SQ - 1 ? SQ - 1 : k);
      va[rr] = *reinterpret_cast<const ushort4*>(&Vbh[(size_t)kc * DH + dg * 4]);
    }
    #pragma unroll
    for (int j = 0; j < 4; ++j) {
      us8 row;
      #pragma unroll
      for (int i = 0; i < 8; ++i)
        row[i] = reinterpret_cast<const unsigned short*>(&va[i])[j];
      *reinterpret_cast<us8*>(&Vt[dg * 4 + j][kg * 8]) = row;
    }
  }
  __syncthreads();

  // ---- per-wave setup ----
  const int q0w = c * 128 + w * 32;
  const int q = q0w + qi;
  const int kw = q0w - WIN;
  bfrag qf[4];
  #pragma unroll
  for (int kk = 0; kk < 4; ++kk)
    qf[kk] = *reinterpret_cast<const bfrag*>(&Qbh[(size_t)q * DH + kk * 16 + h * 8]);

  const int lo = (-q > -WIN) ? -q : -WIN;
  const int hi = (SQ - 1 - q < WIN) ? (SQ - 1 - q) : WIN;
  const int hq = 4 * h - qi;
  const bool edge = (c == 0) || (c == 31);

  f32x16 c0 = {}, c1 = {};
  float m = -3e38f, ls = 0.f;

  for (int kt = 0; kt < 9; ++kt) {
    // K A-frags (clamped rows; invalid keys masked below)
    int krow = kw + kt * 32 + qi;
    int kc = krow < 0 ? 0 : (krow > SQ - 1 ? SQ - 1 : krow);
    bfrag kf[4];
    #pragma unroll
    for (int kk = 0; kk < 4; ++kk)
      kf[kk] = *reinterpret_cast<const bfrag*>(&Kbh[(size_t)kc * DH + kk * 16 + h * 8]);

    f32x16 D = {};
    __builtin_amdgcn_s_setprio(1);
    #pragma unroll
    for (int kk = 0; kk < 4; ++kk)
      D = __builtin_amdgcn_mfma_f32_32x32x16_bf16(kf[kk], qf[kk], D, 0, 0, 0);
    __builtin_amdgcn_s_setprio(0);

    // mask (only boundary tiles / edge blocks need it)
    if (edge || kt == 0 || kt == 8) {
      #pragma unroll
      for (int r = 0; r < 16; ++r) {
        int klocal = (r & 3) + 8 * (r >> 2);
        int dk = kt * 32 + klocal - WIN + hq;
        if (dk < lo || dk > hi) D[r] = -1e30f;
      }
    }

    // tile max (per q column)
    float pm = D[0];
    #pragma unroll
    for (int r = 1; r < 16; ++r) pm = fmaxf(pm, D[r]);
    pm = fmaxf(pm, __shfl_xor(pm, 32));

    // defer-max online rescale
    if (!__all(pm <= m + THR)) {
      float mn = fmaxf(m, pm);
      float al = __builtin_amdgcn_exp2f(m - mn);
      #pragma unroll
      for (int r = 0; r < 16; ++r) {
        float av = __shfl(al, (r & 3) + 8 * (r >> 2) + 4 * h);
        c0[r] *= av; c1[r] *= av;
      }
      ls *= al;
      m = mn;
    }

    // P = exp2(D - m); row-sum partials
    float p[16];
    float sum = 0.f;
    #pragma unroll
    for (int r = 0; r < 16; ++r) {
      p[r] = __builtin_amdgcn_exp2f(D[r] - m);
      sum += p[r];
    }
    ls += sum;

    // convert to bf16 pairs, exchange halves -> PV A-frags
    unsigned U[8];
    #pragma unroll
    for (int g = 0; g < 8; ++g) U[g] = cvtpk(p[2 * g], p[2 * g + 1]);

    unsigned f0[4], f1[4];
    {
      unsigned x, y, xs, ys;
      x = U[0]; y = U[2]; xs = __shfl_xor(x, 32); ys = __shfl_xor(y, 32);
      f0[0] = h ? ys : x;  f0[2] = h ? y : xs;
      x = U[1]; y = U[3]; xs = __shfl_xor(x, 32); ys = __shfl_xor(y, 32);
      f0[1] = h ? ys : x;  f0[3] = h ? y : xs;
      x = U[4]; y = U[6]; xs = __shfl_xor(x, 32); ys = __shfl_xor(y, 32);
      f1[0] = h ? ys : x;  f1[2] = h ? y : xs;
      x = U[5]; y = U[7]; xs = __shfl_xor(x, 32); ys = __shfl_xor(y, 32);
      f1[1] = h ? ys : x;  f1[3] = h ? y : xs;
    }

    // PV: 2 k-steps x 2 d-tiles
    const int colbase = w * 32 + kt * 32;
    bfrag paA, paB;
    {
      uint4 ua = {f0[0], f0[1], f0[2], f0[3]};
      uint4 ub = {f1[0], f1[1], f1[2], f1[3]};
      paA = *reinterpret_cast<bfrag*>(&ua);
      paB = *reinterpret_cast<bfrag*>(&ub);
    }
    bfrag v00 = *reinterpret_cast<const bfrag*>(&Vt[qi][colbase + h * 8]);
    bfrag v01 = *reinterpret_cast<const bfrag*>(&Vt[32 + qi][colbase + h * 8]);
    bfrag v10 = *reinterpret_cast<const bfrag*>(&Vt[qi][colbase + 16 + h * 8]);
    bfrag v11 = *reinterpret_cast<const bfrag*>(&Vt[32 + qi][colbase + 16 + h * 8]);
    __builtin_amdgcn_s_setprio(1);
    c0 = __builtin_amdgcn_mfma_f32_32x32x16_bf16(paA, v00, c0, 0, 0, 0);
    c1 = __builtin_amdgcn_mfma_f32_32x32x16_bf16(paA, v01, c1, 0, 0, 0);
    c0 = __builtin_amdgcn_mfma_f32_32x32x16_bf16(paB, v10, c0, 0, 0, 0);
    c1 = __builtin_amdgcn_mfma_f32_32x32x16_bf16(paB, v11, c1, 0, 0, 0);
    __builtin_amdgcn_s_setprio(0);
  }

  // ---- epilogue: combine l across halves, normalize, write ----
  float lt = ls + __shfl_xor(ls, 32);
  float rinv = 1.0f / lt;
  #pragma unroll
  for (int r = 0; r < 16; ++r) {
    int qrow = (r & 3) + 8 * (r >> 2) + 4 * h;
    float rv = __shfl(rinv, qrow);
    size_t obase = (size_t)(b_ * SQ + q0w + qrow) * HIDN + hd * DH;
    out[obase + qi] = c0[r] * rv;
    out[obase + 32 + qi] = c1[r] * rv;
  }
}

extern "C" void kernel_launch(void* const* d_in, const int* in_sizes, int n_in,
                              void* d_out, int out_size, void* d_ws, size_t ws_size,
                              hipStream_t stream) {
  const float* hid = (const float*)d_in[0];
  const float* Wq  = (const float*)d_in[1];
  const float* bq  = (const float*)d_in[2];
  const float* Wk  = (const float*)d_in[3];
  const float* bk  = (const float*)d_in[4];
  const float* Wv  = (const float*)d_in[5];
  const float* bv  = (const float*)d_in[6];
  float* out = (float*)d_out;

  unsigned short* qb = (unsigned short*)d_ws;
  unsigned short* kb = qb + BHD_ELEMS;
  unsigned short* vb = kb + BHD_ELEMS;
  unsigned short* wb = vb + BHD_ELEMS;
  unsigned short* hb = wb + NCOLS * KDIM;

  int nconv = (NCOLS * KDIM / 4 + 255) / 256;
  wconv_kernel<<<dim3(nconv), dim3(256), 0, stream>>>(Wq, Wk, Wv, wb);
  hconv_kernel<<<dim3(2048), dim3(256), 0, stream>>>(hid, hb);

  dim3 g1(NCOLS * MROWS / (BM * BN));
  proj_kernel<<<g1, dim3(256), 0, stream>>>(hb, wb, bq, bk, bv, qb, kb, vb);

  dim3 g2(SQ / 128, BH);
  attn_kernel<<<g2, dim3(256), 0, stream>>>(qb, kb, vb, out);
}